// Round 1
// baseline (5488.472 us; speedup 1.0000x reference)
//
#include <hip/hip_runtime.h>
#include <hip/hip_bf16.h>
#include <stdint.h>

// Problem dims
#define B_   16
#define T_   4096
#define F_   47
#define HID_ 64
#define CH_  256
#define TG_  1024   // T/4
#define G3_  768    // 3*CH

using bf16x8 = __attribute__((ext_vector_type(8))) short;  // 8 bf16 (4 VGPRs)
using f32x4  = __attribute__((ext_vector_type(4))) float;  // 4 fp32 acc

__device__ __forceinline__ short f2bf(float f) {
    union { float f; uint32_t u; } v; v.f = f;
    uint32_t u = v.u;
    uint32_t r = (u + 0x7fffu + ((u >> 16) & 1u)) >> 16;   // RNE
    return (short)r;
}
__device__ __forceinline__ float bf2f(short s) {
    union { uint32_t u; float f; } v; v.u = ((uint32_t)(uint16_t)s) << 16;
    return v.f;
}
__device__ __forceinline__ float fast_tanh(float x) {
    float e = __expf(2.f * x);           // inf-safe: x>>0 -> 1, x<<0 -> -1
    return 1.f - 2.f / (e + 1.f);
}
__device__ __forceinline__ float fast_sigmoid(float x) {
    return 1.f / (1.f + __expf(-x));
}

// ---------------------------------------------------------------------------
// K1: conv1 (pointwise 47->64) + tanh, fp32 VALU, writes c1 as bf16
// layout c1[(b*1024+tg)*256 + fr*64+h] == flat (b, t, h)
// grid 16384 x 256
__global__ __launch_bounds__(256) void k1_conv1(const float* __restrict__ feat,
        const float* __restrict__ W1, const float* __restrict__ b1,
        short* __restrict__ c1) {
    __shared__ float sW[47 * 64];   // W1 transposed [f][h]
    __shared__ float sF[4 * 47];
    int tid = threadIdx.x;
    int b = blockIdx.x >> 10, t0 = (blockIdx.x & 1023) * 4;
    if (tid < 188) sF[tid] = feat[((size_t)b * T_ + t0) * 47 + tid];
    for (int i = tid; i < 47 * 64; i += 256) {
        int f = i >> 6, h = i & 63;
        sW[i] = W1[h * 47 + f];
    }
    __syncthreads();
    int fr = tid >> 6, h = tid & 63;
    float acc = b1[h];
    #pragma unroll
    for (int f = 0; f < 47; ++f)
        acc += sF[fr * 47 + f] * sW[f * 64 + h];
    c1[((size_t)b * T_ + t0 + fr) * 64 + h] = f2bf(fast_tanh(acc));
}

// ---------------------------------------------------------------------------
// Weight prep: re-layout to B^T (K-contiguous) bf16 for MFMA B-frags.
// grid 1024 x 256 (262144 threads)
__global__ __launch_bounds__(256) void k_prep(const float* __restrict__ W2,
        const float* __restrict__ Wt, const float* __restrict__ Wih_f,
        short* __restrict__ W2t, short* __restrict__ Wtt, short* __restrict__ Wih) {
    int idx = blockIdx.x * 256 + threadIdx.x;
    if (idx < 256 * 512) {           // W2t[o][i], i = d*256 + j  <- W2[o][j][d]
        int o = idx >> 9, i = idx & 511, d = i >> 8, j = i & 255;
        W2t[idx] = f2bf(W2[(size_t)o * 512 + j * 2 + d]);
    }
    {                                // Wtt[n][ic], n = kp*256 + o <- Wt[ic][o][kp]
        int n = idx >> 8, ic = idx & 255, o = n & 255, kp = n >> 8;
        Wtt[idx] = f2bf(Wt[(size_t)ic * 1024 + o * 4 + kp]);
    }
    if (idx < G3_ * CH_)             // W_ih already [g][c] K-contiguous
        Wih[idx] = f2bf(Wih_f[idx]);
}

// ---------------------------------------------------------------------------
// K2: conv2 (k=2 causal) as GEMM M=16384,K=512,N=256 + tanh.
// A rows overlap: row (b,tg) = c1[(b,tg-1)..(b,tg)] contiguous 512 bf16.
// block = 4 waves = 4 M-tiles; grid 256 x 256
__global__ __launch_bounds__(256) void k2_conv2(const short* __restrict__ c1,
        const short* __restrict__ W2t, const float* __restrict__ b2,
        short* __restrict__ y2) {
    int tid = threadIdx.x, w = tid >> 6, l = tid & 63;
    int lane16 = l & 15, quad = l >> 4;
    int mt = blockIdx.x * 4 + w;
    int row = mt * 16 + lane16;
    int tg = row & 1023;
    const short* Arow = c1 + (size_t)row * 256 - 256;
    bf16x8 zero8 = {0,0,0,0,0,0,0,0};
    bf16x8 af[16];
    #pragma unroll
    for (int kt = 0; kt < 16; ++kt) {
        int i0 = kt * 32 + quad * 8;
        bool masked = (tg == 0) && (kt < 8);        // causal zero-pad (per-lane)
        const short* p = masked ? c1 : (Arow + i0); // never read OOB
        bf16x8 v = *(const bf16x8*)p;
        af[kt] = masked ? zero8 : v;
    }
    #pragma unroll
    for (int nt = 0; nt < 16; ++nt) {
        int n = nt * 16 + lane16;
        f32x4 acc = {0.f, 0.f, 0.f, 0.f};
        const short* Brow = W2t + (size_t)n * 512 + quad * 8;
        #pragma unroll
        for (int kt = 0; kt < 16; ++kt) {
            bf16x8 bf = *(const bf16x8*)(Brow + kt * 32);
            acc = __builtin_amdgcn_mfma_f32_16x16x32_bf16(af[kt], bf, acc, 0, 0, 0);
        }
        float bias = b2[n];
        #pragma unroll
        for (int r = 0; r < 4; ++r) {
            int mrow = mt * 16 + quad * 4 + r;      // D row = quad*4+reg
            y2[(size_t)mrow * 256 + n] = f2bf(fast_tanh(acc[r] + bias));
        }
    }
}

// ---------------------------------------------------------------------------
// K3a: tconv as GEMM M=16384,K=256,N=1024 (n = kp*256+o) + tanh -> c3 bf16.
// block = 1 M-tile, 4 waves = 4 N-chunks of 16 tiles; grid 1024 x 256
__global__ __launch_bounds__(256) void k3a_tconv(const short* __restrict__ y2,
        const short* __restrict__ Wtt, const float* __restrict__ bt,
        short* __restrict__ c3) {
    int tid = threadIdx.x, w = tid >> 6, l = tid & 63;
    int lane16 = l & 15, quad = l >> 4;
    int mt = blockIdx.x;
    int row = mt * 16 + lane16;
    const short* Arow = y2 + (size_t)row * 256 + quad * 8;
    bf16x8 af[8];
    #pragma unroll
    for (int kt = 0; kt < 8; ++kt) af[kt] = *(const bf16x8*)(Arow + kt * 32);
    #pragma unroll
    for (int nt2 = 0; nt2 < 16; ++nt2) {
        int n = (w * 16 + nt2) * 16 + lane16;
        f32x4 acc = {0.f, 0.f, 0.f, 0.f};
        const short* Brow = Wtt + (size_t)n * 256 + quad * 8;
        #pragma unroll
        for (int kt = 0; kt < 8; ++kt) {
            bf16x8 bf = *(const bf16x8*)(Brow + kt * 32);
            acc = __builtin_amdgcn_mfma_f32_16x16x32_bf16(af[kt], bf, acc, 0, 0, 0);
        }
        int kp = n >> 8, o = n & 255;
        float bias = bt[o];
        #pragma unroll
        for (int r = 0; r < 4; ++r) {
            int mrow = mt * 16 + quad * 4 + r;
            int bb = mrow >> 10, tgg = mrow & 1023;
            c3[(((size_t)bb * TG_ + tgg) * 4 + kp) * 256 + o] =
                f2bf(fast_tanh(acc[r] + bias));
        }
    }
}

// ---------------------------------------------------------------------------
// K3b: x-projection GEMM M=65536,K=256,N=768 (+b_ih) -> gates bf16.
// block = 1 M-tile, 4 waves x 12 N-tiles; grid 4096 x 256
__global__ __launch_bounds__(256) void k3b_xproj(const short* __restrict__ c3,
        const short* __restrict__ Wih, const float* __restrict__ b_ih,
        short* __restrict__ gates) {
    int tid = threadIdx.x, w = tid >> 6, l = tid & 63;
    int lane16 = l & 15, quad = l >> 4;
    int mt = blockIdx.x;
    int row = mt * 16 + lane16;
    const short* Arow = c3 + (size_t)row * 256 + quad * 8;
    bf16x8 af[8];
    #pragma unroll
    for (int kt = 0; kt < 8; ++kt) af[kt] = *(const bf16x8*)(Arow + kt * 32);
    #pragma unroll
    for (int nt2 = 0; nt2 < 12; ++nt2) {
        int n = (w * 12 + nt2) * 16 + lane16;
        f32x4 acc = {0.f, 0.f, 0.f, 0.f};
        const short* Brow = Wih + (size_t)n * 256 + quad * 8;
        #pragma unroll
        for (int kt = 0; kt < 8; ++kt) {
            bf16x8 bf = *(const bf16x8*)(Brow + kt * 32);
            acc = __builtin_amdgcn_mfma_f32_16x16x32_bf16(af[kt], bf, acc, 0, 0, 0);
        }
        float bias = b_ih[n];
        #pragma unroll
        for (int r = 0; r < 4; ++r) {
            int mrow = mt * 16 + quad * 4 + r;
            gates[(size_t)mrow * G3_ + n] = f2bf(acc[r] + bias);
        }
    }
}

// ---------------------------------------------------------------------------
// K4: persistent GRU. 1 block per batch, 8 waves. W_hh bf16 B-frags in
// registers (48 tiles -> 6 per wave -> 192 VGPR). Per step: 384 MFMAs,
// gh via LDS, gates streamed with 2-step register prefetch.
__global__ __launch_bounds__(512, 2) void k4_gru(const float* __restrict__ W_hh,
        const float* __restrict__ b_hh, const short* __restrict__ gates,
        float* __restrict__ out) {
    __shared__ __align__(16) short h_bf[256];
    __shared__ float gh[G3_];
    __shared__ __align__(16) short gxb[2][G3_];
    int tid = threadIdx.x, w = tid >> 6, l = tid & 63;
    int lane16 = l & 15, quad = l >> 4;
    int b = blockIdx.x;

    // W_hh -> register B-fragments: B[k][n] = W_hh[n][k]
    bf16x8 Bfr[6][8];
    #pragma unroll
    for (int t = 0; t < 6; ++t) {
        int n = (w * 6 + t) * 16 + lane16;
        const float* p = W_hh + (size_t)n * 256 + quad * 8;
        #pragma unroll
        for (int kt = 0; kt < 8; ++kt) {
            const f32x4* q = (const f32x4*)(p + kt * 32);
            f32x4 u0 = q[0], u1 = q[1];
            bf16x8 v;
            v[0] = f2bf(u0[0]); v[1] = f2bf(u0[1]); v[2] = f2bf(u0[2]); v[3] = f2bf(u0[3]);
            v[4] = f2bf(u1[0]); v[5] = f2bf(u1[1]); v[6] = f2bf(u1[2]); v[7] = f2bf(u1[3]);
            Bfr[t][kt] = v;
        }
    }

    float h_reg = 0.f, bhr = 0.f, bhz = 0.f, bhn = 0.f;
    if (tid < 256) {
        h_bf[tid] = 0;
        bhr = b_hh[tid]; bhz = b_hh[256 + tid]; bhn = b_hh[512 + tid];
    }
    const uint32_t* gxg = (const uint32_t*)(gates + (size_t)b * T_ * G3_);
    uint32_t rB = 0, rC = 0;
    if (tid < 384) {
        uint32_t rA = gxg[tid];          // gx[0]
        rB = gxg[384 + tid];             // gx[1]
        ((uint32_t*)&gxb[0][0])[tid] = rA;
    }
    __syncthreads();

    float* outb = out + (size_t)b * T_ * CH_;
    for (int s = 0; s < T_; ++s) {
        rC = 0;
        if (tid < 384 && s + 2 < T_) rC = gxg[(size_t)(s + 2) * 384 + tid];

        // gh = h @ W_hh^T : A rows all hold h (replicated), extract row 0
        f32x4 acc[6];
        #pragma unroll
        for (int t = 0; t < 6; ++t) acc[t] = (f32x4){0.f, 0.f, 0.f, 0.f};
        bf16x8 a_cur = *(const bf16x8*)&h_bf[quad * 8];
        #pragma unroll
        for (int kt = 0; kt < 8; ++kt) {
            bf16x8 a_nxt = a_cur;
            if (kt < 7) a_nxt = *(const bf16x8*)&h_bf[(kt + 1) * 32 + quad * 8];
            #pragma unroll
            for (int t = 0; t < 6; ++t)
                acc[t] = __builtin_amdgcn_mfma_f32_16x16x32_bf16(a_cur, Bfr[t][kt], acc[t], 0, 0, 0);
            a_cur = a_nxt;
        }
        if (l < 16) {   // D row 0 lives in lanes 0..15, reg 0
            #pragma unroll
            for (int t = 0; t < 6; ++t) gh[(w * 6 + t) * 16 + l] = acc[t][0];
        }
        if (tid < 384) ((uint32_t*)&gxb[(s + 1) & 1][0])[tid] = rB;
        __syncthreads();

        if (tid < 256) {
            const short* gx = &gxb[s & 1][0];
            float hr = gh[tid] + bhr;
            float hz = gh[256 + tid] + bhz;
            float hn = gh[512 + tid] + bhn;
            float xr = bf2f(gx[tid]), xz = bf2f(gx[256 + tid]), xn = bf2f(gx[512 + tid]);
            float r = fast_sigmoid(xr + hr);
            float z = fast_sigmoid(xz + hz);
            float nn = fast_tanh(xn + r * hn);
            h_reg = (1.f - z) * nn + z * h_reg;
            h_bf[tid] = f2bf(h_reg);
            outb[(size_t)s * 256 + tid] = h_reg;
        }
        rB = rC;
        __syncthreads();
    }
}

// ---------------------------------------------------------------------------
extern "C" void kernel_launch(void* const* d_in, const int* in_sizes, int n_in,
                              void* d_out, int out_size, void* d_ws, size_t ws_size,
                              hipStream_t stream) {
    const float* feat  = (const float*)d_in[0];
    const float* W1    = (const float*)d_in[1];
    const float* b1    = (const float*)d_in[2];
    const float* W2    = (const float*)d_in[3];
    const float* b2    = (const float*)d_in[4];
    const float* Wt    = (const float*)d_in[5];
    const float* bt    = (const float*)d_in[6];
    const float* Wih_f = (const float*)d_in[7];
    const float* Whh   = (const float*)d_in[8];
    const float* bih   = (const float*)d_in[9];
    const float* bhh   = (const float*)d_in[10];
    float* out = (float*)d_out;

    // ws layout (129.1 MB):
    //   [0, 33.5M)      c3 bf16 (c1 bf16 aliases first 8.4M; c1 dead after K2)
    //   [33.5M, 134.2M) gates bf16 (y2 bf16 aliases first 8.4M; y2 dead after K3a)
    //   [134.2M, ...)   W2t / Wtt / Wih bf16
    char* ws = (char*)d_ws;
    short* c3    = (short*)(ws);
    short* c1    = (short*)(ws);
    short* gates = (short*)(ws + 33554432);
    short* y2    = (short*)(ws + 33554432);
    short* W2t   = (short*)(ws + 134217728);
    short* Wtt   = (short*)(ws + 134217728 + 262144);
    short* Wih   = (short*)(ws + 134217728 + 262144 + 524288);

    k1_conv1 <<<16384, 256, 0, stream>>>(feat, W1, b1, c1);
    k_prep   <<<1024, 256, 0, stream>>>(W2, Wt, Wih_f, W2t, Wtt, Wih);
    k2_conv2 <<<256,  256, 0, stream>>>(c1, W2t, b2, y2);
    k3a_tconv<<<1024, 256, 0, stream>>>(y2, Wtt, bt, c3);     // overwrites c1 (dead)
    k3b_xproj<<<4096, 256, 0, stream>>>(c3, Wih, bih, gates); // overwrites y2 (dead)
    k4_gru   <<<16,   512, 0, stream>>>(Whh, bhh, gates, out);
}